// Round 6
// baseline (84.108 us; speedup 1.0000x reference)
//
#include <hip/hip_runtime.h>

// Blobber: out = sig2(box3(sig1(box3(in)))) — the reference's 4 iterations all
// restart from `inputs`, so they collapse to one iteration.
// in/out: 32 x 1 x 512 x 512 fp32.
//
// R5 post-mortem: correct at ~22 us but 2x over the 10.4 us HBM floor with all
// issue pipes idle -> bandwidth-at-low-occupancy (8 waves/CU, bursty MLP).
// This version: BH=4 -> 4096 waves (16/CU, 4/SIMD), and 8 contiguous px/lane
// so one wave spans the full 512-px row: horizontal exchange = 2 shuffles per
// row-step (lane edges == image edges, literal zero-pad). All 8 input rows
// loaded up front into registers; register-only pipeline; no LDS, no barriers.
//
// Per s1 row r: v3 = in(r-1)+in(r)+in(r+1) (rows zero-padded);
// s1 = sig1(h3(v3)), forced 0 for OOB rows (conv2 zero-pads s1 itself,
// NOT sig1(0)=4.5e-5); h2 = h3(s1); out(y) = sig2(h2(y-1)+h2(y)+h2(y+1)).

#define IMG 512
#define BH  4             // output rows per wave
#define NR  (BH + 4)      // 8 input rows resident in registers
#define NIT (BH + 2)      // 6 s1/h2 rows

// sigmoid((sum9/9 - c)*1000) = sigmoid(fma(sum9, 1000/9, -1000c))
__device__ __forceinline__ float steep_sig(float sum9, float bias) {
    float x = fmaf(sum9, 1000.0f / 9.0f, bias);
    return __builtin_amdgcn_rcpf(1.0f + __expf(-x));
}

__device__ __forceinline__ float4 f4add3(float4 a, float4 b, float4 c) {
    return make_float4(a.x + b.x + c.x, a.y + b.y + c.y,
                       a.z + b.z + c.z, a.w + b.w + c.w);
}

__global__ __launch_bounds__(256, 4) void blobber_fused(const float* __restrict__ in,
                                                        float* __restrict__ out) {
    const int tid  = threadIdx.x;
    const int lane = tid & 63;
    const int gw   = blockIdx.x * 4 + (tid >> 6);   // 4096 waves
    const int band = gw & 127;                      // 128 bands x 4 rows
    const int img  = gw >> 7;                       // 32 images
    const int y0   = band * BH;
    const int xA   = 8 * lane;                      // lane owns cols xA..xA+7

    const float* ip = in  + (size_t)img * (IMG * IMG);
    float*       op = out + (size_t)img * (IMG * IMG);

    // ---- load all 8 input rows (y0-2 .. y0+5), zero for OOB rows ----
    float4 A[NR], B[NR];                            // cols xA..+3 / xA+4..+7
    #pragma unroll
    for (int k = 0; k < NR; ++k) {
        const int r = y0 - 2 + k;
        A[k] = make_float4(0.f, 0.f, 0.f, 0.f);
        B[k] = make_float4(0.f, 0.f, 0.f, 0.f);
        if ((unsigned)r < IMG) {                    // wave-uniform
            const float* row = ip + r * IMG + xA;
            A[k] = *(const float4*)(row);
            B[k] = *(const float4*)(row + 4);
        }
    }

    const float4 z4 = make_float4(0.f, 0.f, 0.f, 0.f);
    float4 h2mA = z4, h2mB = z4, h2cA = z4, h2cB = z4;

    #pragma unroll
    for (int s = 0; s < NIT; ++s) {
        const int r = y0 - 1 + s;                   // s1/h2 row being produced

        // vertical 3-sum (input rows r-1..r+1 = regs s..s+2)
        float4 vA = f4add3(A[s], A[s + 1], A[s + 2]);
        float4 vB = f4add3(B[s], B[s + 1], B[s + 2]);

        // horizontal neighbors: lane-1's px7 and lane+1's px0.
        // Lane 0 / 63 edges are the image edges -> literal 0 (zero pad).
        float lft = __shfl_up(vB.w, 1);
        float rgt = __shfl_down(vA.x, 1);
        if (lane == 0)  lft = 0.0f;
        if (lane == 63) rgt = 0.0f;

        // stage 1: s1 = sig1(h3(v3)); OOB rows are literal 0
        float4 s1A, s1B;
        if ((unsigned)r < IMG) {                    // wave-uniform
            s1A.x = steep_sig(lft  + vA.x + vA.y, -10.0f);
            s1A.y = steep_sig(vA.x + vA.y + vA.z, -10.0f);
            s1A.z = steep_sig(vA.y + vA.z + vA.w, -10.0f);
            s1A.w = steep_sig(vA.z + vA.w + vB.x, -10.0f);
            s1B.x = steep_sig(vA.w + vB.x + vB.y, -10.0f);
            s1B.y = steep_sig(vB.x + vB.y + vB.z, -10.0f);
            s1B.z = steep_sig(vB.y + vB.z + vB.w, -10.0f);
            s1B.w = steep_sig(vB.z + vB.w + rgt,  -10.0f);
        } else {
            s1A = z4; s1B = z4;
        }

        // stage 2 horizontal: h2 = h3(s1)
        float slft = __shfl_up(s1B.w, 1);
        float srgt = __shfl_down(s1A.x, 1);
        if (lane == 0)  slft = 0.0f;
        if (lane == 63) srgt = 0.0f;

        float4 h2pA, h2pB;
        h2pA.x = slft  + s1A.x + s1A.y;
        h2pA.y = s1A.x + s1A.y + s1A.z;
        h2pA.z = s1A.y + s1A.z + s1A.w;
        h2pA.w = s1A.z + s1A.w + s1B.x;
        h2pB.x = s1A.w + s1B.x + s1B.y;
        h2pB.y = s1B.x + s1B.y + s1B.z;
        h2pB.z = s1B.y + s1B.z + s1B.w;
        h2pB.w = s1B.z + s1B.w + srgt;

        // output row r-1 = sig2(vertical 3-sum of h2 rows r-2..r)
        if (s >= 2) {
            const int oy = r - 1;                   // y0 .. y0+3
            float4 oA, oB;
            oA.x = steep_sig(h2mA.x + h2cA.x + h2pA.x, -900.0f);
            oA.y = steep_sig(h2mA.y + h2cA.y + h2pA.y, -900.0f);
            oA.z = steep_sig(h2mA.z + h2cA.z + h2pA.z, -900.0f);
            oA.w = steep_sig(h2mA.w + h2cA.w + h2pA.w, -900.0f);
            oB.x = steep_sig(h2mB.x + h2cB.x + h2pB.x, -900.0f);
            oB.y = steep_sig(h2mB.y + h2cB.y + h2pB.y, -900.0f);
            oB.z = steep_sig(h2mB.z + h2cB.z + h2pB.z, -900.0f);
            oB.w = steep_sig(h2mB.w + h2cB.w + h2pB.w, -900.0f);
            float* orow = op + oy * IMG + xA;
            *(float4*)(orow)     = oA;
            *(float4*)(orow + 4) = oB;
        }

        h2mA = h2cA; h2mB = h2cB;
        h2cA = h2pA; h2cB = h2pB;
    }
}

extern "C" void kernel_launch(void* const* d_in, const int* in_sizes, int n_in,
                              void* d_out, int out_size, void* d_ws, size_t ws_size,
                              hipStream_t stream) {
    const float* in  = (const float*)d_in[0];
    float*       out = (float*)d_out;
    // 4096 waves = 1024 blocks x 4 waves (32 imgs x 128 bands)
    blobber_fused<<<dim3(1024), dim3(256), 0, stream>>>(in, out);
}